// Round 4
// baseline (9462.090 us; speedup 1.0000x reference)
//
#include <hip/hip_runtime.h>
#include <cstddef>

// ---------------------------------------------------------------------------
// SNN forward, feed-forward pipeline. CORRECTNESS CONTRACT (R2 post-mortem):
// the v>0.33 Heaviside amplifies ANY accumulation-order change into spike
// flips vs the numpy reference (R2's exact-integer MFMA failed at 2.4e-2
// despite being MORE accurate). All arithmetic chains here are verbatim
// R3 (which passed at absmax 1.5e-5): sequential-in-j fp32 fmaf with
// av in {0, scale}, encoder/LIF/LI loops unchanged. R4 restructures only:
//   - W pre-transposed to [j][o] once -> chunk staging is flat float4 copies
//     (contiguous ds_write_b128, no scalar LDS transpose)
//   - gates via sbfe sign-splat (2 VALU, bitwise-identical av)
//   - LIF/bit-transpose FUSED into gemm epilogue (block owns all 32 t + full
//     J) -> no H global round-trip, no lif/tmask/out_li kernels
//   - encoder fused with its bit-transpose -> writes emT directly
// ---------------------------------------------------------------------------

#define THREADS 256

#if __has_builtin(__builtin_amdgcn_sbfe)
#define BIT_SPLAT(m, j) __builtin_amdgcn_sbfe((int)(m), (unsigned)(j), 1u)
#else
#define BIT_SPLAT(m, j) (((int)((m) << (31 - (j)))) >> 31)
#endif

// WT offsets (floats): WT1[2048][512], WT2[512][512], WT3[512][256],
// WT4[256][128] (w4 zero-padded 100->128 cols)
#define WOFF1 0
#define WOFF2 1048576
#define WOFF3 1310720
#define WOFF4 1441792
#define WTOT  1474560

__global__ __launch_bounds__(THREADS) void prep_kernel(
    const float* __restrict__ w1, const float* __restrict__ w2,
    const float* __restrict__ w3, const float* __restrict__ w4,
    float* __restrict__ wt)
{
  int idx = blockIdx.x * THREADS + threadIdx.x;
  if (idx >= WTOT) return;
  if (idx < WOFF2) {
    int j = idx >> 9, o = idx & 511;
    wt[idx] = w1[o * 2048 + j];
  } else if (idx < WOFF3) {
    int r = idx - WOFF2, j = r >> 9, o = r & 511;
    wt[idx] = w2[o * 512 + j];
  } else if (idx < WOFF4) {
    int r = idx - WOFF3, j = r >> 8, o = r & 255;
    wt[idx] = w3[o * 512 + j];
  } else {
    int r = idx - WOFF4, j = r >> 7, o = r & 127;
    wt[idx] = (o < 100) ? w4[o * 256 + j] : 0.0f;
  }
}

// Encoder (verbatim R3 arithmetic) fused with 32x32 bit-transpose:
// writes emT word(b, c, t) = bits over jj (j = c*32+jj).
__global__ __launch_bounds__(THREADS) void enc_kernel(
    const float* __restrict__ x, const float* __restrict__ fscale,
    unsigned* __restrict__ emT, int b0)
{
  __shared__ unsigned sm[8][33];
  int tile = threadIdx.x >> 5, l = threadIdx.x & 31;
  size_t gt = (size_t)blockIdx.x * 8 + tile;     // gt = b*64 + c
  int c = (int)(gt & 63);
  size_t b = gt >> 6;
  float cc = 2.0f * fscale[0] * x[((size_t)(b0 + b) << 11) + c * 32 + l];
  float v = 0.0f;
  unsigned m = 0u;
#pragma unroll
  for (int t = 0; t < 32; ++t) {
    v = v + 0.1f * (cc - v);
    unsigned z = ((v - 0.33f) > 0.0f) ? 1u : 0u;
    m |= z << t;
    if (z) v = 0.0f;
  }
  sm[tile][l] = m;
  __syncthreads();
  unsigned w = 0;
#pragma unroll
  for (int jj = 0; jj < 32; ++jj) w |= ((sm[tile][jj] >> l) & 1u) << jj;
  emT[(gt << 5) + l] = w;
}

// ---------------------------------------------------------------------------
// Fused GEMM(+LIF / +LI readout).
//   mT:  bit-transposed input masks, word (b, c, t) = bits over jj
//   WT:  [j][o] pre-transposed weights
// Block: OTILE o x BB b x all 32 t. Thread: t = tid&31, og = tid>>5,
// acc[BB][OTILE/8]. Epilogue per bb: acc -> LDS (t,o) tile -> verbatim LIF
// integration per o -> 32x32 bit-transpose -> mTout (or LI readout -> out).
// ---------------------------------------------------------------------------
template <int OTILE, int BB, bool FINAL>
__global__ __launch_bounds__(THREADS, 3) void gemm_fused(
    const unsigned* __restrict__ mT, const float* __restrict__ WT,
    int J, int O, const float* __restrict__ es,
    unsigned* __restrict__ mTout, int ncO,
    float* __restrict__ out, int bbase)
{
  constexpr int OVEC = OTILE / 8;
  constexpr int F4PT = OTILE / 32;           // staged float4 per thread
  constexpr int RS = OTILE + 1;              // padded epilogue row stride
  __shared__ float sbuf[32 * RS];
  const int tid = threadIdx.x;
  const int t = tid & 31, og = tid >> 5;
  const int o0 = blockIdx.x * OTILE;
  const int btile = blockIdx.y * BB;
  const int nc = J >> 5;
  const float scale = es ? 5.0f * es[0] : 1.0f;   // same expr as R3
  const int scale_i = __float_as_int(scale);

  float acc[BB][OVEC];
#pragma unroll
  for (int bb = 0; bb < BB; ++bb)
#pragma unroll
    for (int oo = 0; oo < OVEC; ++oo) acc[bb][oo] = 0.0f;

  for (int c = 0; c < nc; ++c) {
    unsigned m[BB];
#pragma unroll
    for (int bb = 0; bb < BB; ++bb)
      m[bb] = mT[(((size_t)(btile + bb) * nc + c) << 5) + t];

    __syncthreads();
    // stage WT chunk rows [c*32 .. +32) x [o0 .. o0+OTILE): flat f4 copy;
    // wave = consecutive fi -> one contiguous 1KB row slice, b128 LDS writes.
    float4 f[F4PT];
#pragma unroll
    for (int i = 0; i < F4PT; ++i) {
      int fi = tid + i * THREADS;
      int j = fi / (OTILE / 4), col = fi % (OTILE / 4);
      f[i] = *(const float4*)(WT + (size_t)(c * 32 + j) * O + o0 + col * 4);
    }
#pragma unroll
    for (int i = 0; i < F4PT; ++i)
      ((float4*)sbuf)[tid + i * THREADS] = f[i];
    __syncthreads();

#pragma unroll 8
    for (int j = 0; j < 32; ++j) {
      float wv[OVEC];
#pragma unroll
      for (int q = 0; q < OVEC / 4; ++q)
        *(float4*)&wv[q * 4] =
            *(const float4*)&sbuf[j * OTILE + og * OVEC + q * 4];
#pragma unroll
      for (int bb = 0; bb < BB; ++bb) {
        // av = bit ? scale : 0.0f (sign-splat AND; bitwise-identical to R3)
        float av = __int_as_float(BIT_SPLAT(m[bb], j) & scale_i);
#pragma unroll
        for (int oo = 0; oo < OVEC; ++oo)
          acc[bb][oo] = fmaf(av, wv[oo], acc[bb][oo]);
      }
    }
  }

  // ---- epilogue: per bb, (t,o) transpose + verbatim LIF / LI ----
#pragma unroll 1
  for (int bb = 0; bb < BB; ++bb) {
    __syncthreads();   // previous sbuf reads done
#pragma unroll
    for (int k = 0; k < OVEC; ++k)
      sbuf[t * RS + og * OVEC + k] = acc[bb][k];   // bank (t+const)%32: free
    __syncthreads();
    if (FINAL) {
      if (tid < OTILE) {
        float v = 0.0f, cur = 0.0f;
#pragma unroll
        for (int t2 = 0; t2 < 32; ++t2) {          // verbatim R3 out_li
          v = v + 0.1f * (cur - v);
          cur = 0.8f * cur + sbuf[t2 * RS + tid];
        }
        if (tid < 100)
          out[(size_t)(bbase + btile + bb) * 100 + tid] = v;
      }
    } else {
      unsigned w = 0;
      if (tid < OTILE) {
        float v = 0.0f, cur = 0.0f;
#pragma unroll
        for (int t2 = 0; t2 < 32; ++t2) {          // verbatim R3 lif_int
          v = v + 0.1f * (cur - v);
          unsigned z = ((v - 0.33f) > 0.0f) ? 1u : 0u;
          w |= z << t2;
          if (z) v = 0.0f;
          cur = 0.8f * cur + sbuf[t2 * RS + tid];
        }
      }
      __syncthreads();
      if (tid < OTILE) ((unsigned*)sbuf)[tid] = w;
      __syncthreads();
      if (tid < OTILE) {
        int cg = tid >> 5, tl = tid & 31;
        unsigned W2 = 0;
#pragma unroll
        for (int jj = 0; jj < 32; ++jj)
          W2 |= ((((unsigned*)sbuf)[cg * 32 + jj] >> tl) & 1u) << jj;
        mTout[((size_t)(btile + bb) * ncO + (o0 >> 5) + cg) * 32 + tl] = W2;
      }
    }
  }
}

extern "C" void kernel_launch(void* const* d_in, const int* in_sizes, int n_in,
                              void* d_out, int out_size, void* d_ws, size_t ws_size,
                              hipStream_t stream)
{
  const float* x  = (const float*)d_in[0];
  const float* w1 = (const float*)d_in[1];
  const float* w2 = (const float*)d_in[2];
  const float* w3 = (const float*)d_in[3];
  const float* w4 = (const float*)d_in[4];
  const float* fs = (const float*)d_in[5];
  const float* es = (const float*)d_in[6];
  float* out = (float*)d_out;
  (void)in_sizes; (void)n_in; (void)out_size;

  // ws: WT (5.9 MB) + emT + s1mT + s2mT + s3mT   (no H buffers needed)
  int Bc = 2048;
  auto need = [](int bc) -> size_t {
    return ((size_t)WTOT + (size_t)bc * (2048 + 512 + 512 + 256)) * 4;
  };
  while (Bc > 64 && need(Bc) > ws_size) Bc >>= 1;

  float* WT = (float*)d_ws;
  unsigned* emT  = (unsigned*)(WT + WTOT);
  unsigned* s1mT = emT  + (size_t)Bc * 2048;
  unsigned* s2mT = s1mT + (size_t)Bc * 512;
  unsigned* s3mT = s2mT + (size_t)Bc * 512;

  prep_kernel<<<(WTOT + THREADS - 1) / THREADS, THREADS, 0, stream>>>(
      w1, w2, w3, w4, WT);

  for (int b0 = 0; b0 < 2048; b0 += Bc) {
    enc_kernel<<<Bc * 8, THREADS, 0, stream>>>(x, fs, emT, b0);
    // L1: J=2048 -> O=512, scale = 5*encoder_scalar
    gemm_fused<256, 4, false><<<dim3(2, Bc / 4), THREADS, 0, stream>>>(
        emT, WT + WOFF1, 2048, 512, es, s1mT, 16, nullptr, 0);
    // L2: J=512 -> O=512
    gemm_fused<256, 4, false><<<dim3(2, Bc / 4), THREADS, 0, stream>>>(
        s1mT, WT + WOFF2, 512, 512, nullptr, s2mT, 16, nullptr, 0);
    // L3: J=512 -> O=256
    gemm_fused<256, 4, false><<<dim3(1, Bc / 4), THREADS, 0, stream>>>(
        s2mT, WT + WOFF3, 512, 256, nullptr, s3mT, 8, nullptr, 0);
    // L4 (readout): J=256 -> O=128 (padded), LI epilogue -> out
    gemm_fused<128, 4, true><<<dim3(1, Bc / 4), THREADS, 0, stream>>>(
        s3mT, WT + WOFF4, 256, 128, nullptr, nullptr, 0, out, b0);
  }
}

// Round 5
// 2291.332 us; speedup vs baseline: 4.1295x; 4.1295x over previous
//
#include <hip/hip_runtime.h>
#include <cstddef>

// ---------------------------------------------------------------------------
// SNN forward, feed-forward pipeline. CORRECTNESS CONTRACT (R2 post-mortem):
// the v>0.33 Heaviside amplifies ANY accumulation-order change into spike
// flips vs the numpy reference (R2's exact-integer MFMA failed at 2.4e-2
// despite being MORE accurate). All arithmetic chains are verbatim R3
// (passed, absmax 1.5e-5): sequential-in-j fp32 fmaf with av in {0,scale};
// encoder/LIF/LI loops unchanged. Per-acc-element op sequence is identical;
// only scheduling/structure differs.
//
// R4 post-mortem: '#pragma unroll 1' on the epilogue made acc runtime-indexed
// -> compiler demoted acc to scratch -> 22.7 GB/dispatch spill traffic
// (VGPR 84 < 128 accs, VALUBusy 15%). R5: epilogue fully unrolled (static
// indices), launch_bounds(256,2), register prefetch of next chunk's W+masks
// to overlap L2 latency with the FMA loop, av cached + o-halves to cut VGPRs.
// ---------------------------------------------------------------------------

#define THREADS 256

#if __has_builtin(__builtin_amdgcn_sbfe)
#define BIT_SPLAT(m, j) __builtin_amdgcn_sbfe((int)(m), (unsigned)(j), 1u)
#else
#define BIT_SPLAT(m, j) (((int)((m) << (31 - (j)))) >> 31)
#endif

// WT offsets (floats): WT1[2048][512], WT2[512][512], WT3[512][256],
// WT4[256][128] (w4 zero-padded 100->128 cols)
#define WOFF1 0
#define WOFF2 1048576
#define WOFF3 1310720
#define WOFF4 1441792
#define WTOT  1474560

__global__ __launch_bounds__(THREADS) void prep_kernel(
    const float* __restrict__ w1, const float* __restrict__ w2,
    const float* __restrict__ w3, const float* __restrict__ w4,
    float* __restrict__ wt)
{
  int idx = blockIdx.x * THREADS + threadIdx.x;
  if (idx >= WTOT) return;
  if (idx < WOFF2) {
    int j = idx >> 9, o = idx & 511;
    wt[idx] = w1[o * 2048 + j];
  } else if (idx < WOFF3) {
    int r = idx - WOFF2, j = r >> 9, o = r & 511;
    wt[idx] = w2[o * 512 + j];
  } else if (idx < WOFF4) {
    int r = idx - WOFF3, j = r >> 8, o = r & 255;
    wt[idx] = w3[o * 512 + j];
  } else {
    int r = idx - WOFF4, j = r >> 7, o = r & 127;
    wt[idx] = (o < 100) ? w4[o * 256 + j] : 0.0f;
  }
}

// Encoder (verbatim R3 arithmetic) fused with 32x32 bit-transpose:
// writes emT word(b, c, t) = bits over jj (j = c*32+jj).
__global__ __launch_bounds__(THREADS) void enc_kernel(
    const float* __restrict__ x, const float* __restrict__ fscale,
    unsigned* __restrict__ emT, int b0)
{
  __shared__ unsigned sm[8][33];
  int tile = threadIdx.x >> 5, l = threadIdx.x & 31;
  size_t gt = (size_t)blockIdx.x * 8 + tile;     // gt = b*64 + c
  int c = (int)(gt & 63);
  size_t b = gt >> 6;
  float cc = 2.0f * fscale[0] * x[((size_t)(b0 + b) << 11) + c * 32 + l];
  float v = 0.0f;
  unsigned m = 0u;
#pragma unroll
  for (int t = 0; t < 32; ++t) {
    v = v + 0.1f * (cc - v);
    unsigned z = ((v - 0.33f) > 0.0f) ? 1u : 0u;
    m |= z << t;
    if (z) v = 0.0f;
  }
  sm[tile][l] = m;
  __syncthreads();
  unsigned w = 0;
#pragma unroll
  for (int jj = 0; jj < 32; ++jj) w |= ((sm[tile][jj] >> l) & 1u) << jj;
  emT[(gt << 5) + l] = w;
}

// ---------------------------------------------------------------------------
// Fused GEMM(+LIF / +LI readout).
//   mT:  bit-transposed input masks, word (b, c, t) = bits over jj
//   WT:  [j][o] pre-transposed weights
// Block: OTILE o x BB b x all 32 t. Thread: t = tid&31, og = tid>>5,
// acc[BB][OTILE/8]. Next chunk's W/masks prefetched into registers during
// the FMA loop. Epilogue (fully unrolled, static acc indices!): per bb,
// acc -> LDS (t,o) tile -> verbatim LIF per o -> 32x32 bit-transpose ->
// mTout (or LI readout -> out).
// ---------------------------------------------------------------------------
template <int OTILE, int BB, bool FINAL>
__global__ __launch_bounds__(THREADS, 2) void gemm_fused(
    const unsigned* __restrict__ mT, const float* __restrict__ WT,
    int J, int O, const float* __restrict__ es,
    unsigned* __restrict__ mTout, int ncO,
    float* __restrict__ out, int bbase)
{
  constexpr int OVEC = OTILE / 8;
  constexpr int OH = OVEC / 2;               // o-half per pass
  constexpr int F4PT = OTILE / 32;           // staged float4 per thread
  constexpr int OQ = OTILE / 4;              // float4 per j-row
  constexpr int RS = OTILE + 1;              // padded epilogue row stride
  __shared__ float sbuf[32 * RS];
  const int tid = threadIdx.x;
  const int t = tid & 31, og = tid >> 5;
  const int o0 = blockIdx.x * OTILE;
  const int btile = blockIdx.y * BB;
  const int nc = J >> 5;
  const float scale = es ? 5.0f * es[0] : 1.0f;   // same expr as R3
  const int scale_i = __float_as_int(scale);

  float acc[BB][OVEC];
#pragma unroll
  for (int bb = 0; bb < BB; ++bb)
#pragma unroll
    for (int oo = 0; oo < OVEC; ++oo) acc[bb][oo] = 0.0f;

  // prologue: chunk-0 masks + W into registers
  unsigned m[BB];
  float4 f[F4PT];
#pragma unroll
  for (int bb = 0; bb < BB; ++bb)
    m[bb] = mT[(((size_t)(btile + bb) * nc) << 5) + t];
#pragma unroll
  for (int i = 0; i < F4PT; ++i) {
    int fi = tid + i * THREADS;
    f[i] = *(const float4*)(WT + (size_t)(fi / OQ) * O + o0 + (fi % OQ) * 4);
  }

#pragma unroll 2
  for (int c = 0; c < nc; ++c) {
    __syncthreads();                           // prior sbuf reads done
#pragma unroll
    for (int i = 0; i < F4PT; ++i)
      ((float4*)sbuf)[tid + i * THREADS] = f[i];
    __syncthreads();

    // prefetch chunk c+1 (clamped; overlaps with FMA loop below)
    const int cn = (c + 1 < nc) ? (c + 1) : c;
    unsigned mn[BB];
    float4 fn[F4PT];
#pragma unroll
    for (int bb = 0; bb < BB; ++bb)
      mn[bb] = mT[(((size_t)(btile + bb) * nc + cn) << 5) + t];
#pragma unroll
    for (int i = 0; i < F4PT; ++i) {
      int fi = tid + i * THREADS;
      fn[i] = *(const float4*)(WT + (size_t)(cn * 32 + fi / OQ) * O + o0 +
                               (fi % OQ) * 4);
    }

#pragma unroll 8
    for (int j = 0; j < 32; ++j) {
      float av[BB];
#pragma unroll
      for (int bb = 0; bb < BB; ++bb)   // av = bit ? scale : 0 (bit-identical)
        av[bb] = __int_as_float(BIT_SPLAT(m[bb], j) & scale_i);
#pragma unroll
      for (int h = 0; h < 2; ++h) {
        float wv[OH];
#pragma unroll
        for (int q = 0; q < OH / 4; ++q)
          *(float4*)&wv[q * 4] =
              *(const float4*)&sbuf[j * OTILE + og * OVEC + h * OH + q * 4];
#pragma unroll
        for (int bb = 0; bb < BB; ++bb)
#pragma unroll
          for (int oo = 0; oo < OH; ++oo)
            acc[bb][h * OH + oo] = fmaf(av[bb], wv[oo], acc[bb][h * OH + oo]);
      }
    }

#pragma unroll
    for (int bb = 0; bb < BB; ++bb) m[bb] = mn[bb];
#pragma unroll
    for (int i = 0; i < F4PT; ++i) f[i] = fn[i];
  }

  // ---- epilogue: per bb, (t,o) transpose + verbatim LIF / LI ----
  // FULLY unrolled: acc indices must stay static (R4 spill post-mortem).
#pragma unroll
  for (int bb = 0; bb < BB; ++bb) {
    __syncthreads();
#pragma unroll
    for (int k = 0; k < OVEC; ++k)
      sbuf[t * RS + og * OVEC + k] = acc[bb][k];
    __syncthreads();
    if (FINAL) {
      if (tid < OTILE) {
        float v = 0.0f, cur = 0.0f;
#pragma unroll
        for (int t2 = 0; t2 < 32; ++t2) {          // verbatim R3 out_li
          v = v + 0.1f * (cur - v);
          cur = 0.8f * cur + sbuf[t2 * RS + tid];
        }
        if (tid < 100)
          out[(size_t)(bbase + btile + bb) * 100 + tid] = v;
      }
    } else {
      unsigned w = 0;
      if (tid < OTILE) {
        float v = 0.0f, cur = 0.0f;
#pragma unroll
        for (int t2 = 0; t2 < 32; ++t2) {          // verbatim R3 lif_int
          v = v + 0.1f * (cur - v);
          unsigned z = ((v - 0.33f) > 0.0f) ? 1u : 0u;
          w |= z << t2;
          if (z) v = 0.0f;
          cur = 0.8f * cur + sbuf[t2 * RS + tid];
        }
      }
      __syncthreads();
      if (tid < OTILE) ((unsigned*)sbuf)[tid] = w;
      __syncthreads();
      if (tid < OTILE) {
        int cg = tid >> 5, tl = tid & 31;
        unsigned W2 = 0;
#pragma unroll
        for (int jj = 0; jj < 32; ++jj)
          W2 |= ((((unsigned*)sbuf)[cg * 32 + jj] >> tl) & 1u) << jj;
        mTout[((size_t)(btile + bb) * ncO + (o0 >> 5) + cg) * 32 + tl] = W2;
      }
    }
  }
}

extern "C" void kernel_launch(void* const* d_in, const int* in_sizes, int n_in,
                              void* d_out, int out_size, void* d_ws, size_t ws_size,
                              hipStream_t stream)
{
  const float* x  = (const float*)d_in[0];
  const float* w1 = (const float*)d_in[1];
  const float* w2 = (const float*)d_in[2];
  const float* w3 = (const float*)d_in[3];
  const float* w4 = (const float*)d_in[4];
  const float* fs = (const float*)d_in[5];
  const float* es = (const float*)d_in[6];
  float* out = (float*)d_out;
  (void)in_sizes; (void)n_in; (void)out_size;

  // ws: WT (5.9 MB) + emT + s1mT + s2mT + s3mT
  int Bc = 2048;
  auto need = [](int bc) -> size_t {
    return ((size_t)WTOT + (size_t)bc * (2048 + 512 + 512 + 256)) * 4;
  };
  while (Bc > 64 && need(Bc) > ws_size) Bc >>= 1;

  float* WT = (float*)d_ws;
  unsigned* emT  = (unsigned*)(WT + WTOT);
  unsigned* s1mT = emT  + (size_t)Bc * 2048;
  unsigned* s2mT = s1mT + (size_t)Bc * 512;
  unsigned* s3mT = s2mT + (size_t)Bc * 512;

  prep_kernel<<<(WTOT + THREADS - 1) / THREADS, THREADS, 0, stream>>>(
      w1, w2, w3, w4, WT);

  for (int b0 = 0; b0 < 2048; b0 += Bc) {
    enc_kernel<<<Bc * 8, THREADS, 0, stream>>>(x, fs, emT, b0);
    // L1: J=2048 -> O=512, scale = 5*encoder_scalar
    gemm_fused<256, 4, false><<<dim3(2, Bc / 4), THREADS, 0, stream>>>(
        emT, WT + WOFF1, 2048, 512, es, s1mT, 16, nullptr, 0);
    // L2: J=512 -> O=512
    gemm_fused<256, 4, false><<<dim3(2, Bc / 4), THREADS, 0, stream>>>(
        s1mT, WT + WOFF2, 512, 512, nullptr, s2mT, 16, nullptr, 0);
    // L3: J=512 -> O=256
    gemm_fused<256, 4, false><<<dim3(1, Bc / 4), THREADS, 0, stream>>>(
        s2mT, WT + WOFF3, 512, 256, nullptr, s3mT, 8, nullptr, 0);
    // L4 (readout): J=256 -> O=128 (padded), LI epilogue -> out
    gemm_fused<128, 4, true><<<dim3(1, Bc / 4), THREADS, 0, stream>>>(
        s3mT, WT + WOFF4, 256, 128, nullptr, nullptr, 0, out, b0);
  }
}

// Round 6
// 2045.381 us; speedup vs baseline: 4.6261x; 1.1202x over previous
//
#include <hip/hip_runtime.h>
#include <cstddef>

// ---------------------------------------------------------------------------
// SNN forward, feed-forward pipeline. CORRECTNESS CONTRACT (R2 post-mortem):
// the v>0.33 Heaviside amplifies ANY accumulation-order change into spike
// flips vs the numpy reference (R2's exact-integer MFMA failed at 2.4e-2
// despite being MORE accurate). All arithmetic chains are verbatim R3
// (passed, absmax 1.5e-5): per (t,b,o), sequential-in-ascending-j fp32 fmaf
// with av in {0,scale}; encoder/LIF/LI loops unchanged.
//
// R4 post-mortem: runtime-indexed acc -> scratch spill (22.7 GB writes).
// R5 post-mortem: register prefetch (64 staging VGPRs) overflowed the unified
// VGPR/AGPR budget -> ~616 MB spill writes, VALUBusy 67%.
// R6: __builtin_amdgcn_global_load_lds (width 16) double-buffered W staging:
// NO staging registers at all, ONE barrier per chunk, loads for chunk c+1 fly
// during chunk c's FMA loop and are drained by the barrier's implicit
// vmcnt(0). Only masks (8 words) are register-prefetched. OTILE=128/BB=8
// halves ds_read pressure at equal acc count.
// ---------------------------------------------------------------------------

#define THREADS 256

#if __has_builtin(__builtin_amdgcn_sbfe)
#define BIT_SPLAT(m, j) __builtin_amdgcn_sbfe((int)(m), (unsigned)(j), 1u)
#else
#define BIT_SPLAT(m, j) (((int)((m) << (31 - (j)))) >> 31)
#endif

__device__ __forceinline__ void gl_lds16(const float* g, float* l) {
#if __has_builtin(__builtin_amdgcn_global_load_lds)
  __builtin_amdgcn_global_load_lds(
      (const __attribute__((address_space(1))) void*)g,
      (__attribute__((address_space(3))) void*)l, 16, 0, 0);
#else
  *(float4*)l = *(const float4*)g;   // sync fallback (correct, slower)
#endif
}

// WT offsets (floats): WT1[2048][512], WT2[512][512], WT3[512][256],
// WT4[256][128] (w4 zero-padded 100->128 cols)
#define WOFF1 0
#define WOFF2 1048576
#define WOFF3 1310720
#define WOFF4 1441792
#define WTOT  1474560

__global__ __launch_bounds__(THREADS) void prep_kernel(
    const float* __restrict__ w1, const float* __restrict__ w2,
    const float* __restrict__ w3, const float* __restrict__ w4,
    float* __restrict__ wt)
{
  int idx = blockIdx.x * THREADS + threadIdx.x;
  if (idx >= WTOT) return;
  if (idx < WOFF2) {
    int j = idx >> 9, o = idx & 511;
    wt[idx] = w1[o * 2048 + j];
  } else if (idx < WOFF3) {
    int r = idx - WOFF2, j = r >> 9, o = r & 511;
    wt[idx] = w2[o * 512 + j];
  } else if (idx < WOFF4) {
    int r = idx - WOFF3, j = r >> 8, o = r & 255;
    wt[idx] = w3[o * 512 + j];
  } else {
    int r = idx - WOFF4, j = r >> 7, o = r & 127;
    wt[idx] = (o < 100) ? w4[o * 256 + j] : 0.0f;
  }
}

// Encoder (verbatim R3 arithmetic) fused with 32x32 bit-transpose:
// writes emT word(b, c, t) = bits over jj (j = c*32+jj).
__global__ __launch_bounds__(THREADS) void enc_kernel(
    const float* __restrict__ x, const float* __restrict__ fscale,
    unsigned* __restrict__ emT, int b0)
{
  __shared__ unsigned sm[8][33];
  int tile = threadIdx.x >> 5, l = threadIdx.x & 31;
  size_t gt = (size_t)blockIdx.x * 8 + tile;     // gt = b*64 + c
  int c = (int)(gt & 63);
  size_t b = gt >> 6;
  float cc = 2.0f * fscale[0] * x[((size_t)(b0 + b) << 11) + c * 32 + l];
  float v = 0.0f;
  unsigned m = 0u;
#pragma unroll
  for (int t = 0; t < 32; ++t) {
    v = v + 0.1f * (cc - v);
    unsigned z = ((v - 0.33f) > 0.0f) ? 1u : 0u;
    m |= z << t;
    if (z) v = 0.0f;
  }
  sm[tile][l] = m;
  __syncthreads();
  unsigned w = 0;
#pragma unroll
  for (int jj = 0; jj < 32; ++jj) w |= ((sm[tile][jj] >> l) & 1u) << jj;
  emT[(gt << 5) + l] = w;
}

// ---------------------------------------------------------------------------
// Fused GEMM(+LIF / +LI readout), async double-buffered W staging.
//   mT:  bit-transposed input masks, word (b, c, t) = bits over jj
//   WT:  [j][o] pre-transposed weights
// Block: OTILE o x BB b x all 32 t. Thread: t = tid&31, og = tid>>5,
// acc[BB][OTILE/8] (static indices only!). Epilogue per bb: acc -> LDS (t,o)
// tile -> verbatim LIF per o -> 32x32 bit-transpose -> mTout (or LI -> out).
// ---------------------------------------------------------------------------
template <int OTILE, int BB, bool FINAL>
__global__ __launch_bounds__(THREADS, 2) void gemm_fused(
    const unsigned* __restrict__ mT, const float* __restrict__ WT,
    int J, int O, const float* __restrict__ es,
    unsigned* __restrict__ mTout, int ncO,
    float* __restrict__ out, int bbase)
{
  constexpr int OVEC = OTILE / 8;
  constexpr int RS = OTILE + 1;              // padded epilogue row stride
  constexpr int CH = 32 * OTILE;             // floats per chunk buffer
  __shared__ float lds[2 * CH];
  static_assert(32 * RS <= 2 * CH, "epilogue overlay fits");
  const int tid = threadIdx.x;
  const int t = tid & 31, og = tid >> 5;
  const int lane = tid & 63, wv = tid >> 6;
  const int o0 = blockIdx.x * OTILE;
  const int btile = blockIdx.y * BB;
  const int nc = J >> 5;
  const float scale = es ? 5.0f * es[0] : 1.0f;   // same expr as R3
  const int scale_i = __float_as_int(scale);
  float* const buf0 = lds;
  float* const buf1 = lds + CH;

  float acc[BB][OVEC];
#pragma unroll
  for (int bb = 0; bb < BB; ++bb)
#pragma unroll
    for (int oo = 0; oo < OVEC; ++oo) acc[bb][oo] = 0.0f;

  // async-stage one 32 x OTILE W chunk: 64 lanes x 16 B per instruction,
  // LDS dest = uniform base + lane*16 (contiguous row-major), no VGPR staging
  auto stage = [&](int c, float* buf) {
    constexpr int IPW = CH / 256 / 4;        // instructions per wave
#pragma unroll
    for (int i = 0; i < IPW; ++i) {
      int inst = wv * IPW + i;
      int flat = inst * 256 + lane * 4;
      int j = flat / OTILE, col = flat % OTILE;
      gl_lds16(WT + (size_t)(c * 32 + j) * O + o0 + col, buf + flat);
    }
  };
  auto loadm = [&](int c, unsigned* md) {
#pragma unroll
    for (int bb = 0; bb < BB; ++bb)
      md[bb] = mT[(((size_t)(btile + bb) * nc + c) << 5) + t];
  };
  auto fma_chunk = [&](const float* buf, const unsigned* m) {
#pragma unroll 8
    for (int j = 0; j < 32; ++j) {
      float av[BB];
#pragma unroll
      for (int bb = 0; bb < BB; ++bb)   // av = bit ? scale : 0 (bit-identical)
        av[bb] = __int_as_float(BIT_SPLAT(m[bb], j) & scale_i);
#pragma unroll
      for (int q = 0; q < OVEC / 4; ++q) {
        const float4 w4 = *(const float4*)&buf[j * OTILE + og * OVEC + q * 4];
        const float wvv[4] = {w4.x, w4.y, w4.z, w4.w};
#pragma unroll
        for (int bb = 0; bb < BB; ++bb)
#pragma unroll
          for (int oo = 0; oo < 4; ++oo)
            acc[bb][q * 4 + oo] = fmaf(av[bb], wvv[oo], acc[bb][q * 4 + oo]);
      }
    }
  };

  unsigned m[BB], mn[BB];
  loadm(0, m);
  stage(0, buf0);

  for (int c = 0; c < nc; c += 2) {          // nc is even (64/16/16/8)
    __syncthreads();                         // buf0 loads drained; buf1 free
    if (c + 1 < nc) { stage(c + 1, buf1); loadm(c + 1, mn); }
    fma_chunk(buf0, m);
#pragma unroll
    for (int bb = 0; bb < BB; ++bb) m[bb] = mn[bb];
    __syncthreads();                         // buf1 loads drained; buf0 free
    if (c + 2 < nc) { stage(c + 2, buf0); loadm(c + 2, mn); }
    fma_chunk(buf1, m);
#pragma unroll
    for (int bb = 0; bb < BB; ++bb) m[bb] = mn[bb];
  }

  // ---- epilogue: per bb, (t,o) transpose + verbatim LIF / LI ----
  // FULLY unrolled: acc indices must stay static (R4 spill post-mortem).
  float* const sbuf = lds;
#pragma unroll
  for (int bb = 0; bb < BB; ++bb) {
    __syncthreads();
#pragma unroll
    for (int k = 0; k < OVEC; ++k)
      sbuf[t * RS + og * OVEC + k] = acc[bb][k];
    __syncthreads();
    if (FINAL) {
      if (tid < OTILE) {
        float v = 0.0f, cur = 0.0f;
#pragma unroll
        for (int t2 = 0; t2 < 32; ++t2) {          // verbatim R3 out_li
          v = v + 0.1f * (cur - v);
          cur = 0.8f * cur + sbuf[t2 * RS + tid];
        }
        if (tid < 100)
          out[(size_t)(bbase + btile + bb) * 100 + tid] = v;
      }
    } else {
      unsigned w = 0;
      if (tid < OTILE) {
        float v = 0.0f, cur = 0.0f;
#pragma unroll
        for (int t2 = 0; t2 < 32; ++t2) {          // verbatim R3 lif_int
          v = v + 0.1f * (cur - v);
          unsigned z = ((v - 0.33f) > 0.0f) ? 1u : 0u;
          w |= z << t2;
          if (z) v = 0.0f;
          cur = 0.8f * cur + sbuf[t2 * RS + tid];
        }
      }
      __syncthreads();
      if (tid < OTILE) ((unsigned*)sbuf)[tid] = w;
      __syncthreads();
      if (tid < OTILE) {
        int cg = tid >> 5, tl = tid & 31;
        unsigned W2 = 0;
#pragma unroll
        for (int jj = 0; jj < 32; ++jj)
          W2 |= ((((unsigned*)sbuf)[cg * 32 + jj] >> tl) & 1u) << jj;
        mTout[((size_t)(btile + bb) * ncO + (o0 >> 5) + cg) * 32 + tl] = W2;
      }
    }
  }
}

extern "C" void kernel_launch(void* const* d_in, const int* in_sizes, int n_in,
                              void* d_out, int out_size, void* d_ws, size_t ws_size,
                              hipStream_t stream)
{
  const float* x  = (const float*)d_in[0];
  const float* w1 = (const float*)d_in[1];
  const float* w2 = (const float*)d_in[2];
  const float* w3 = (const float*)d_in[3];
  const float* w4 = (const float*)d_in[4];
  const float* fs = (const float*)d_in[5];
  const float* es = (const float*)d_in[6];
  float* out = (float*)d_out;
  (void)in_sizes; (void)n_in; (void)out_size;

  // ws: WT (5.9 MB) + emT + s1mT + s2mT + s3mT
  int Bc = 2048;
  auto need = [](int bc) -> size_t {
    return ((size_t)WTOT + (size_t)bc * (2048 + 512 + 512 + 256)) * 4;
  };
  while (Bc > 64 && need(Bc) > ws_size) Bc >>= 1;

  float* WT = (float*)d_ws;
  unsigned* emT  = (unsigned*)(WT + WTOT);
  unsigned* s1mT = emT  + (size_t)Bc * 2048;
  unsigned* s2mT = s1mT + (size_t)Bc * 512;
  unsigned* s3mT = s2mT + (size_t)Bc * 512;

  prep_kernel<<<(WTOT + THREADS - 1) / THREADS, THREADS, 0, stream>>>(
      w1, w2, w3, w4, WT);

  for (int b0 = 0; b0 < 2048; b0 += Bc) {
    enc_kernel<<<Bc * 8, THREADS, 0, stream>>>(x, fs, emT, b0);
    // L1: J=2048 -> O=512, scale = 5*encoder_scalar
    gemm_fused<128, 8, false><<<dim3(4, Bc / 8), THREADS, 0, stream>>>(
        emT, WT + WOFF1, 2048, 512, es, s1mT, 16, nullptr, 0);
    // L2: J=512 -> O=512
    gemm_fused<128, 8, false><<<dim3(4, Bc / 8), THREADS, 0, stream>>>(
        s1mT, WT + WOFF2, 512, 512, nullptr, s2mT, 16, nullptr, 0);
    // L3: J=512 -> O=256
    gemm_fused<128, 8, false><<<dim3(2, Bc / 8), THREADS, 0, stream>>>(
        s2mT, WT + WOFF3, 512, 256, nullptr, s3mT, 8, nullptr, 0);
    // L4 (readout): J=256 -> O=128 (padded), LI epilogue -> out
    gemm_fused<128, 8, true><<<dim3(1, Bc / 8), THREADS, 0, stream>>>(
        s3mT, WT + WOFF4, 256, 128, nullptr, nullptr, 0, out, b0);
  }
}